// Round 1
// baseline (3171.913 us; speedup 1.0000x reference)
//
#include <hip/hip_runtime.h>
#include <math.h>

// Problem constants
// x: [2, 2048, 1024] f32; w_attn: [1024, 3072]; b_attn: [3072];
// w_proj: [1024, 1024]; b_proj: [1024]; out: [2, 2048, 1024] f32
#define BATCH 2
#define SEQ   2048
#define EMBD  1024
#define NHEAD 16
#define HDIM  64
#define M_ROWS (BATCH * SEQ)   // 4096

// ---------------------------------------------------------------------------
// GEMM: out[M,N] = A[M,K] @ W[K,N] + bias[N]   (fp32, tiled 64x64x16)
// 256 threads, each computes a 4x4 micro-tile.
// A-tile stored k-major with float4-level XOR swizzle to keep writes and
// reads <=2-way bank conflicts (free on CDNA4 per measured m136).
// ---------------------------------------------------------------------------
__global__ __launch_bounds__(256) void gemm_bias_f32(
    const float* __restrict__ A, const float* __restrict__ W,
    const float* __restrict__ bias, float* __restrict__ out,
    int M, int N, int K) {
  __shared__ float As[16 * 64];  // [k][m] swizzled: col stored at m ^ ((k&15)<<2)
  __shared__ float Bs[16 * 64];  // [k][n] linear

  const int tid = threadIdx.x;
  const int tx = tid & 15;        // 0..15 -> output col group
  const int ty = tid >> 4;        // 0..15 -> output row group
  const int row0 = blockIdx.y * 64;
  const int col0 = blockIdx.x * 64;

  float acc[4][4] = {};

  for (int k0 = 0; k0 < K; k0 += 16) {
    // --- load A tile: thread loads one float4 along k ---
    {
      const int m = tid >> 2;          // 0..63
      const int k4 = tid & 3;          // float4 index along k
      const float4 a4 = *reinterpret_cast<const float4*>(
          &A[(size_t)(row0 + m) * K + k0 + k4 * 4]);
      const float av[4] = {a4.x, a4.y, a4.z, a4.w};
#pragma unroll
      for (int kk = 0; kk < 4; ++kk) {
        const int k = k4 * 4 + kk;
        As[k * 64 + (m ^ ((k & 15) << 2))] = av[kk];
      }
    }
    // --- load B tile: thread loads one float4 along n ---
    {
      const int n4 = tid & 15;
      const int kb = tid >> 4;         // 0..15
      const float4 b4 = *reinterpret_cast<const float4*>(
          &W[(size_t)(k0 + kb) * N + col0 + n4 * 4]);
      *reinterpret_cast<float4*>(&Bs[kb * 64 + n4 * 4]) = b4;
    }
    __syncthreads();

#pragma unroll
    for (int k = 0; k < 16; ++k) {
      const float4 av = *reinterpret_cast<const float4*>(
          &As[k * 64 + ((ty * 4) ^ (k << 2))]);
      const float4 bv = *reinterpret_cast<const float4*>(&Bs[k * 64 + tx * 4]);
      const float a[4] = {av.x, av.y, av.z, av.w};
      const float b[4] = {bv.x, bv.y, bv.z, bv.w};
#pragma unroll
      for (int i = 0; i < 4; ++i)
#pragma unroll
        for (int j = 0; j < 4; ++j) acc[i][j] += a[i] * b[j];
    }
    __syncthreads();
  }

  const float4 bias4 = *reinterpret_cast<const float4*>(&bias[col0 + tx * 4]);
  const float bb[4] = {bias4.x, bias4.y, bias4.z, bias4.w};
#pragma unroll
  for (int i = 0; i < 4; ++i) {
    float4 o;
    o.x = acc[i][0] + bb[0];
    o.y = acc[i][1] + bb[1];
    o.z = acc[i][2] + bb[2];
    o.w = acc[i][3] + bb[3];
    *reinterpret_cast<float4*>(
        &out[(size_t)(row0 + ty * 4 + i) * N + col0 + tx * 4]) = o;
  }
}

// ---------------------------------------------------------------------------
// Flash-style causal attention.
// grid: (T/64 q-tiles, B*H). 256 threads = 64 q-rows x 4 col-groups.
// Thread (r, sub): owns q-row r, score cols c = sub*16+j, output dims
// d = sub*16..sub*16+15. Online softmax state replicated across the 4
// lanes of a row (consecutive lanes -> __shfl_xor 1,2 reduces).
// K/V tiles in LDS with float4-level XOR swizzle on (c>>2)&15 so the
// 4 distinct row-addresses per read instruction land on distinct banks.
// ---------------------------------------------------------------------------
__device__ __forceinline__ int kv_f4(int c, int d4) {
  return c * 16 + (d4 ^ ((c >> 2) & 15));  // float4 index within 64x64 tile
}

__global__ __launch_bounds__(256) void attn_causal_f32(
    const float* __restrict__ qkv, float* __restrict__ y) {
  const int qi = blockIdx.x;       // q tile 0..31
  const int bh = blockIdx.y;       // 0..31
  const int b = bh >> 4, h = bh & 15;
  const int C3 = 3 * EMBD;

  const float* base = qkv + (size_t)b * SEQ * C3;
  const int qoff = h * HDIM;
  const int koff = EMBD + h * HDIM;
  const int voff = 2 * EMBD + h * HDIM;

  const int tid = threadIdx.x;
  const int r = tid >> 2;          // local q row 0..63
  const int sub = tid & 3;         // 0..3
  const int grow = qi * 64 + r;    // global q row

  __shared__ float Ks[64 * 64];
  __shared__ float Vs[64 * 64];

  // Q row in registers (64 floats as 16 float4), replicated over 4 lanes
  float4 qreg[16];
  {
    const float* qrow = base + (size_t)grow * C3 + qoff;
#pragma unroll
    for (int i = 0; i < 16; ++i)
      qreg[i] = *reinterpret_cast<const float4*>(qrow + i * 4);
  }

  float m = -1e30f, l = 0.f;
  float o[16] = {};
  const float scale = 0.125f;  // 1/sqrt(64)

  for (int kt = 0; kt <= qi; ++kt) {
    // --- stage K,V tile: wave loads full 64-float rows (coalesced) ---
#pragma unroll
    for (int i = 0; i < 16; ++i) {
      const int e = tid + i * 256;
      const int c = e >> 6;
      const int d = e & 63;
      const float* krow = base + (size_t)(kt * 64 + c) * C3;
      const int pos = kv_f4(c, d >> 2) * 4 + (d & 3);
      Ks[pos] = krow[koff + d];
      Vs[pos] = krow[voff + d];
    }
    __syncthreads();

    // --- scores for my 16 columns ---
    float p[16];
    float mt = -1e30f;
#pragma unroll
    for (int j = 0; j < 16; ++j) {
      const int c = sub * 16 + j;
      float s = 0.f;
#pragma unroll
      for (int i = 0; i < 16; ++i) {
        const float4 kv =
            *reinterpret_cast<const float4*>(&Ks[kv_f4(c, i) * 4]);
        s += qreg[i].x * kv.x + qreg[i].y * kv.y + qreg[i].z * kv.z +
             qreg[i].w * kv.w;
      }
      s *= scale;
      if (kt == qi && (kt * 64 + c) > grow) s = -1e30f;  // causal mask
      p[j] = s;
      mt = fmaxf(mt, s);
    }
    // row max across the 4 lanes of this row
    mt = fmaxf(mt, __shfl_xor(mt, 1));
    mt = fmaxf(mt, __shfl_xor(mt, 2));
    const float mnew = fmaxf(m, mt);
    const float alpha = __expf(m - mnew);
    float lsum = 0.f;
#pragma unroll
    for (int j = 0; j < 16; ++j) {
      p[j] = __expf(p[j] - mnew);
      lsum += p[j];
    }
    lsum += __shfl_xor(lsum, 1);
    lsum += __shfl_xor(lsum, 2);
    l = l * alpha + lsum;
    m = mnew;
#pragma unroll
    for (int i = 0; i < 16; ++i) o[i] *= alpha;

    // --- PV: pull each row's 64 probabilities via intra-group shuffle ---
#pragma unroll
    for (int src = 0; src < 4; ++src) {
#pragma unroll
      for (int j = 0; j < 16; ++j) {
        const float pv = __shfl(p[j], (tid & ~3) | src, 64);
        const int c = src * 16 + j;
#pragma unroll
        for (int i = 0; i < 4; ++i) {
          const float4 vv = *reinterpret_cast<const float4*>(
              &Vs[kv_f4(c, sub * 4 + i) * 4]);
          o[i * 4 + 0] += pv * vv.x;
          o[i * 4 + 1] += pv * vv.y;
          o[i * 4 + 2] += pv * vv.z;
          o[i * 4 + 3] += pv * vv.w;
        }
      }
    }
    __syncthreads();
  }

  const float inv = 1.f / l;
  float* yrow = y + (size_t)(b * SEQ + grow) * EMBD + h * HDIM + sub * 16;
#pragma unroll
  for (int i = 0; i < 16; ++i) yrow[i] = o[i] * inv;
}

// ---------------------------------------------------------------------------
extern "C" void kernel_launch(void* const* d_in, const int* in_sizes, int n_in,
                              void* d_out, int out_size, void* d_ws,
                              size_t ws_size, hipStream_t stream) {
  const float* x      = (const float*)d_in[0];
  const float* w_attn = (const float*)d_in[1];
  const float* b_attn = (const float*)d_in[2];
  const float* w_proj = (const float*)d_in[3];
  const float* b_proj = (const float*)d_in[4];
  float* out = (float*)d_out;

  float* qkv = (float*)d_ws;                       // [4096][3072]
  float* y   = qkv + (size_t)M_ROWS * 3 * EMBD;    // [4096][1024]

  dim3 blk(256);
  // 1) qkv = x @ w_attn + b_attn
  gemm_bias_f32<<<dim3(3 * EMBD / 64, M_ROWS / 64), blk, 0, stream>>>(
      x, w_attn, b_attn, qkv, M_ROWS, 3 * EMBD, EMBD);
  // 2) y = causal_attention(qkv)
  attn_causal_f32<<<dim3(SEQ / 64, BATCH * NHEAD), blk, 0, stream>>>(qkv, y);
  // 3) out = y @ w_proj + b_proj
  gemm_bias_f32<<<dim3(EMBD / 64, M_ROWS / 64), blk, 0, stream>>>(
      y, w_proj, b_proj, out, M_ROWS, EMBD, EMBD);
}

// Round 2
// 227.335 us; speedup vs baseline: 13.9526x; 13.9526x over previous
//
#include <hip/hip_runtime.h>
#include <stdint.h>

// B=2, T=2048, C=1024, H=16, D=64
#define SEQ   2048
#define EMBD  1024
#define M_ROWS 4096

typedef unsigned short u16;
typedef unsigned int u32;
typedef __attribute__((ext_vector_type(8))) short bf16x8;
typedef __attribute__((ext_vector_type(4))) float f32x4;

__device__ __forceinline__ u16 f2b(float f) {  // f32 -> bf16 RNE
  u32 x = __float_as_uint(f);
  return (u16)((x + 0x7FFFu + ((x >> 16) & 1u)) >> 16);
}

#define AS1(p) ((const __attribute__((address_space(1))) void*)(uintptr_t)(p))
#define AS3(p) ((__attribute__((address_space(3))) void*)(uintptr_t)(p))

// ---------------------------------------------------------------------------
// fp32 -> bf16 bulk convert (8 elems/thread)
// ---------------------------------------------------------------------------
__global__ __launch_bounds__(256) void cvt_f32_bf16(
    const float* __restrict__ in, u16* __restrict__ out, int n8) {
  int i = blockIdx.x * 256 + threadIdx.x;
  if (i >= n8) return;
  const float4* p = (const float4*)in + 2 * (size_t)i;
  float4 a = p[0], b = p[1];
  uint4 o;
  o.x = (u32)f2b(a.x) | ((u32)f2b(a.y) << 16);
  o.y = (u32)f2b(a.z) | ((u32)f2b(a.w) << 16);
  o.z = (u32)f2b(b.x) | ((u32)f2b(b.y) << 16);
  o.w = (u32)f2b(b.z) | ((u32)f2b(b.w) << 16);
  ((uint4*)out)[i] = o;
}

// ---------------------------------------------------------------------------
// wt[n][k] = bf16(w[k][n])  — 64x64 LDS tile transpose (+1 pad, conflict-free)
// grid: (N/64, K/64)
// ---------------------------------------------------------------------------
__global__ __launch_bounds__(256) void transpose_cvt(
    const float* __restrict__ w, u16* __restrict__ wt, int K, int N) {
  __shared__ float t[64][65];
  const int n0 = blockIdx.x * 64, k0 = blockIdx.y * 64;
  const int c = threadIdx.x & 63, r4 = threadIdx.x >> 6;
#pragma unroll
  for (int j = 0; j < 16; ++j) {
    const int r = j * 4 + r4;
    t[c][r] = w[(size_t)(k0 + r) * N + n0 + c];
  }
  __syncthreads();
#pragma unroll
  for (int j = 0; j < 16; ++j) {
    const int nr = j * 4 + r4;
    wt[(size_t)(n0 + nr) * K + k0 + c] = f2b(t[nr][c]);
  }
}

// ---------------------------------------------------------------------------
// bf16 MFMA GEMM, m97 structure: 128x128 tile, BK=32, 4 waves (2x2 of 64x64).
// A[M][K], Bt[N][K] both bf16 K-major. out = A @ Bt^T + bias.
// LDS rows 64B, XOR swizzle kbyte ^= ((row&3)<<4); staged via global_load_lds
// with pre-swizzled global source (guideline 21).
// ---------------------------------------------------------------------------
template <bool OUT_BF16>
__global__ __launch_bounds__(256) void gemm_kmajor(
    const u16* __restrict__ A, const u16* __restrict__ Bt,
    const float* __restrict__ bias, void* __restrict__ outp,
    int M, int N, int K, int nbx) {
  __shared__ __align__(16) u16 As[128 * 32];
  __shared__ __align__(16) u16 Bs[128 * 32];

  // bijective XCD swizzle (m204)
  const int nwg = gridDim.x;
  const int qq = nwg >> 3, rr = nwg & 7;
  const int xcd = blockIdx.x & 7, off = blockIdx.x >> 3;
  const int wgid = (xcd < rr ? xcd * (qq + 1) : rr * (qq + 1) + (xcd - rr) * qq) + off;
  const int bx = wgid % nbx, by = wgid / nbx;
  const int row0 = by * 128, col0 = bx * 128;

  const int tid = threadIdx.x;
  const int w = tid >> 6, lane = tid & 63;
  const int wrow = (w >> 1) * 64, wcol = (w & 1) * 64;

  f32x4 acc[4][4];
#pragma unroll
  for (int a = 0; a < 4; ++a)
#pragma unroll
    for (int b = 0; b < 4; ++b)
#pragma unroll
      for (int e = 0; e < 4; ++e) acc[a][b][e] = 0.f;

  const size_t Kb = (size_t)K * 2;

  for (int k0 = 0; k0 < K; k0 += 32) {
    // stage: waves 0,1 -> A chunks 0..7; waves 2,3 -> B chunks 0..7
#pragma unroll
    for (int c = 0; c < 4; ++c) {
      const int ch = w * 4 + c;
      const int i = ch & 7;
      const int rloc = i * 16 + (lane >> 2);
      const int kb = ((lane & 3) * 16) ^ ((rloc & 3) << 4);  // pre-swizzled src
      const char* src;
      char* dst;
      if (ch < 8) {
        src = (const char*)A + (size_t)(row0 + rloc) * Kb + k0 * 2 + kb;
        dst = (char*)As + i * 1024;
      } else {
        src = (const char*)Bt + (size_t)(col0 + rloc) * Kb + k0 * 2 + kb;
        dst = (char*)Bs + i * 1024;
      }
      __builtin_amdgcn_global_load_lds(AS1(src), AS3(dst), 16, 0, 0);
    }
    __syncthreads();

    bf16x8 af[4], bf[4];
#pragma unroll
    for (int rb = 0; rb < 4; ++rb) {
      const int rl = wrow + rb * 16 + (lane & 15);
      const int kb2 = ((lane >> 4) * 16) ^ ((rl & 3) << 4);
      af[rb] = *(const bf16x8*)((const char*)As + rl * 64 + kb2);
    }
#pragma unroll
    for (int cb = 0; cb < 4; ++cb) {
      const int rl = wcol + cb * 16 + (lane & 15);
      const int kb2 = ((lane >> 4) * 16) ^ ((rl & 3) << 4);
      bf[cb] = *(const bf16x8*)((const char*)Bs + rl * 64 + kb2);
    }
#pragma unroll
    for (int rb = 0; rb < 4; ++rb)
#pragma unroll
      for (int cb = 0; cb < 4; ++cb)
        acc[rb][cb] = __builtin_amdgcn_mfma_f32_16x16x32_bf16(
            af[rb], bf[cb], acc[rb][cb], 0, 0, 0);
    __syncthreads();
  }

  // epilogue: C/D layout col=lane&15, row=(lane>>4)*4+i (m89-verified)
#pragma unroll
  for (int cb = 0; cb < 4; ++cb) {
    const int colg = col0 + wcol + cb * 16 + (lane & 15);
    const float bv = bias[colg];
#pragma unroll
    for (int rb = 0; rb < 4; ++rb) {
#pragma unroll
      for (int i = 0; i < 4; ++i) {
        const int rowg = row0 + wrow + rb * 16 + (lane >> 4) * 4 + i;
        const float v = acc[rb][cb][i] + bv;
        if (OUT_BF16) {
          const u32 hv = f2b(v);
          const u32 pv = (u32)__shfl_xor((int)hv, 1);
          if (!(lane & 1))
            *(u32*)((u16*)outp + (size_t)rowg * N + colg) = hv | (pv << 16);
        } else {
          ((float*)outp)[(size_t)rowg * N + colg] = v;
        }
      }
    }
  }
}

// ---------------------------------------------------------------------------
// Flash attention, bf16 MFMA. Block = 64 q-rows (16/wave), K/V tile = 64.
// qkvb: [B*T][3C] bf16 (from GEMM1). yb: [B*T][C] bf16, [b,t,h,d] layout.
// ---------------------------------------------------------------------------
__global__ __launch_bounds__(256) void attn_mfma(
    const u16* __restrict__ qkvb, u16* __restrict__ yb) {
  __shared__ __align__(16) u16 Ks[64 * 64];       // [kv][d], swz ((kv&7)<<4) bytes
  __shared__ __align__(16) u16 Vt[64 * 64];       // [d][kv], swz ((d&7)<<3) elems
  __shared__ __align__(16) u16 Ps[4][16 * 64];    // per-wave P, swz ((row&7)<<3)

  const int bx = blockIdx.x;
  const int qt = 31 - (bx >> 5);   // longest blocks first
  const int bh = bx & 31;
  const int bb = bh >> 4, h = bh & 15;

  const int tid = threadIdx.x;
  const int w = tid >> 6, lane = tid & 63;

  const size_t rowb = 3072 * 2;
  const char* base = (const char*)qkvb + (size_t)bb * SEQ * rowb;
  const int qoffb = h * 128;
  const int koffb = EMBD * 2 + h * 128;
  const int voffb = 2 * EMBD * 2 + h * 128;

  // Q fragments (A-layout: row=lane&15, k=8*(lane>>4)+e)
  bf16x8 qf[2];
  {
    const int qrow = qt * 64 + w * 16 + (lane & 15);
    const char* qp = base + (size_t)qrow * rowb + qoffb + (lane >> 4) * 16;
    qf[0] = *(const bf16x8*)(qp);
    qf[1] = *(const bf16x8*)(qp + 64);
  }

  float mreg[4], lreg[4];
  f32x4 of[4];
#pragma unroll
  for (int i = 0; i < 4; ++i) {
    mreg[i] = -1e30f;
    lreg[i] = 0.f;
#pragma unroll
    for (int e = 0; e < 4; ++e) of[i][e] = 0.f;
  }

  const int vkv = tid & 63, vdb = tid >> 6;

  for (int kt = 0; kt <= qt; ++kt) {
    // --- stage K: 8 chunks of 1024B via global_load_lds, pre-swizzled src ---
#pragma unroll
    for (int c = 0; c < 2; ++c) {
      const int i = w * 2 + c;
      const int kv = i * 8 + (lane >> 3);
      const int db = ((lane & 7) * 16) ^ ((kv & 7) << 4);
      const char* src = base + (size_t)(kt * 64 + kv) * rowb + koffb + db;
      __builtin_amdgcn_global_load_lds(AS1(src), AS3((char*)Ks + i * 1024), 16, 0, 0);
    }
    // --- stage V transposed: Vt[d][kv] ---
    {
      const char* vp = base + (size_t)(kt * 64 + vkv) * rowb + voffb + vdb * 32;
      union { uint4 q4[2]; u16 hh[16]; } vv;
      vv.q4[0] = *(const uint4*)vp;
      vv.q4[1] = *(const uint4*)(vp + 16);
#pragma unroll
      for (int e = 0; e < 16; ++e) {
        const int d = vdb * 16 + e;
        Vt[d * 64 + (vkv ^ ((d & 7) << 3))] = vv.hh[e];
      }
    }
    __syncthreads();

    // --- S = Q K^T (B-frag: col=kv=lane&15, k=d) ---
    f32x4 s[4];
#pragma unroll
    for (int cb = 0; cb < 4; ++cb)
#pragma unroll
      for (int e = 0; e < 4; ++e) s[cb][e] = 0.f;
#pragma unroll
    for (int cb = 0; cb < 4; ++cb) {
      const int kv = cb * 16 + (lane & 15);
      const int swz = (kv & 7) << 4;
      const char* kp = (const char*)Ks + kv * 128;
      bf16x8 kf0 = *(const bf16x8*)(kp + (((lane >> 4) * 16) ^ swz));
      bf16x8 kf1 = *(const bf16x8*)(kp + ((64 + (lane >> 4) * 16) ^ swz));
      s[cb] = __builtin_amdgcn_mfma_f32_16x16x32_bf16(qf[0], kf0, s[cb], 0, 0, 0);
      s[cb] = __builtin_amdgcn_mfma_f32_16x16x32_bf16(qf[1], kf1, s[cb], 0, 0, 0);
    }

    // --- scale + causal mask + row max (rows live in 16-lane groups) ---
    const int qg0 = qt * 64 + w * 16 + (lane >> 4) * 4;  // + i
    const int kvg0 = kt * 64 + (lane & 15);              // + cb*16
    float pmax[4] = {-1e30f, -1e30f, -1e30f, -1e30f};
#pragma unroll
    for (int cb = 0; cb < 4; ++cb)
#pragma unroll
      for (int i = 0; i < 4; ++i) {
        float v = s[cb][i] * 0.125f;
        if (kvg0 + cb * 16 > qg0 + i) v = -1e30f;
        s[cb][i] = v;
        pmax[i] = fmaxf(pmax[i], v);
      }
#pragma unroll
    for (int i = 0; i < 4; ++i) {
      pmax[i] = fmaxf(pmax[i], __shfl_xor(pmax[i], 1));
      pmax[i] = fmaxf(pmax[i], __shfl_xor(pmax[i], 2));
      pmax[i] = fmaxf(pmax[i], __shfl_xor(pmax[i], 4));
      pmax[i] = fmaxf(pmax[i], __shfl_xor(pmax[i], 8));
    }
    float alpha[4], rsum[4];
#pragma unroll
    for (int i = 0; i < 4; ++i) {
      const float mn = fmaxf(mreg[i], pmax[i]);
      alpha[i] = __expf(mreg[i] - mn);
      mreg[i] = mn;
      rsum[i] = 0.f;
    }
    // --- P = exp(S - m) -> LDS (bf16, swizzled) ---
#pragma unroll
    for (int cb = 0; cb < 4; ++cb)
#pragma unroll
      for (int i = 0; i < 4; ++i) {
        const float p = __expf(s[cb][i] - mreg[i]);
        rsum[i] += p;
        const int prow = (lane >> 4) * 4 + i;
        const int pcol = cb * 16 + (lane & 15);
        Ps[w][prow * 64 + (pcol ^ ((prow & 7) << 3))] = f2b(p);
      }
#pragma unroll
    for (int i = 0; i < 4; ++i) {
      rsum[i] += __shfl_xor(rsum[i], 1);
      rsum[i] += __shfl_xor(rsum[i], 2);
      rsum[i] += __shfl_xor(rsum[i], 4);
      rsum[i] += __shfl_xor(rsum[i], 8);
      lreg[i] = lreg[i] * alpha[i] + rsum[i];
    }
#pragma unroll
    for (int db = 0; db < 4; ++db)
#pragma unroll
      for (int i = 0; i < 4; ++i) of[db][i] *= alpha[i];

    // --- O += P V  (A=P from LDS; B=V from Vt[d][kv]) ---
    bf16x8 pa[2];
    {
      const int prow = lane & 15;
      const int swz = (prow & 7) << 3;
      pa[0] = *(const bf16x8*)(&Ps[w][prow * 64 + ((8 * (lane >> 4)) ^ swz)]);
      pa[1] = *(const bf16x8*)(&Ps[w][prow * 64 + ((8 * (lane >> 4) + 32) ^ swz)]);
    }
#pragma unroll
    for (int db = 0; db < 4; ++db) {
      const int d = db * 16 + (lane & 15);
      const int swz = (d & 7) << 3;
      const u16* vp = &Vt[d * 64];
      bf16x8 v0 = *(const bf16x8*)(vp + ((8 * (lane >> 4)) ^ swz));
      bf16x8 v1 = *(const bf16x8*)(vp + ((8 * (lane >> 4) + 32) ^ swz));
      of[db] = __builtin_amdgcn_mfma_f32_16x16x32_bf16(pa[0], v0, of[db], 0, 0, 0);
      of[db] = __builtin_amdgcn_mfma_f32_16x16x32_bf16(pa[1], v1, of[db], 0, 0, 0);
    }
    __syncthreads();
  }

  // --- epilogue: y = O / l ---
#pragma unroll
  for (int i = 0; i < 4; ++i) lreg[i] = 1.f / lreg[i];
  const int qrow0 = qt * 64 + w * 16 + (lane >> 4) * 4;
#pragma unroll
  for (int db = 0; db < 4; ++db) {
    const int colb = h * 64 + db * 16 + (lane & 15);
#pragma unroll
    for (int i = 0; i < 4; ++i) {
      const float v = of[db][i] * lreg[i];
      yb[(size_t)(bb * SEQ + qrow0 + i) * EMBD + colb] = f2b(v);
    }
  }
}

// ---------------------------------------------------------------------------
extern "C" void kernel_launch(void* const* d_in, const int* in_sizes, int n_in,
                              void* d_out, int out_size, void* d_ws,
                              size_t ws_size, hipStream_t stream) {
  const float* x      = (const float*)d_in[0];
  const float* w_attn = (const float*)d_in[1];
  const float* b_attn = (const float*)d_in[2];
  const float* w_proj = (const float*)d_in[3];
  const float* b_proj = (const float*)d_in[4];
  float* out = (float*)d_out;

  u16* xb   = (u16*)d_ws;                          //  8 MB  [4096][1024]
  u16* wat  = xb + (size_t)M_ROWS * EMBD;          //  6 MB  [3072][1024]
  u16* wpt  = wat + (size_t)3 * EMBD * EMBD;       //  2 MB  [1024][1024]
  u16* qkvb = wpt + (size_t)EMBD * EMBD;           // 24 MB  [4096][3072]
  u16* yb   = qkvb + (size_t)M_ROWS * 3 * EMBD;    //  8 MB  [4096][1024]

  cvt_f32_bf16<<<(M_ROWS * EMBD / 8 + 255) / 256, 256, 0, stream>>>(
      x, xb, M_ROWS * EMBD / 8);
  transpose_cvt<<<dim3(3 * EMBD / 64, EMBD / 64), 256, 0, stream>>>(
      w_attn, wat, EMBD, 3 * EMBD);
  transpose_cvt<<<dim3(EMBD / 64, EMBD / 64), 256, 0, stream>>>(
      w_proj, wpt, EMBD, EMBD);

  gemm_kmajor<true><<<768, 256, 0, stream>>>(
      xb, wat, b_attn, qkvb, M_ROWS, 3 * EMBD, EMBD, 24);

  attn_mfma<<<1024, 256, 0, stream>>>(qkvb, yb);

  gemm_kmajor<false><<<256, 256, 0, stream>>>(
      yb, wpt, b_proj, out, M_ROWS, EMBD, EMBD, 8);
}

// Round 3
// 207.650 us; speedup vs baseline: 15.2753x; 1.0948x over previous
//
#include <hip/hip_runtime.h>
#include <stdint.h>

// B=2, T=2048, C=1024, H=16, D=64
#define SEQ   2048
#define EMBD  1024
#define M_ROWS 4096

typedef unsigned short u16;
typedef unsigned int u32;
typedef __attribute__((ext_vector_type(8))) short bf16x8;
typedef __attribute__((ext_vector_type(4))) float f32x4;

__device__ __forceinline__ u16 f2b(float f) {  // f32 -> bf16 RNE
  u32 x = __float_as_uint(f);
  return (u16)((x + 0x7FFFu + ((x >> 16) & 1u)) >> 16);
}

__device__ __forceinline__ u32 pkbf(float a, float b) {  // pack 2xf32 -> 2xbf16
  u32 r;
  asm("v_cvt_pk_bf16_f32 %0, %1, %2" : "=v"(r) : "v"(a), "v"(b));
  return r;
}

__device__ __forceinline__ float exp2fast(float x) {
#if __has_builtin(__builtin_amdgcn_exp2f)
  return __builtin_amdgcn_exp2f(x);
#else
  return __expf(x * 0.69314718f);
#endif
}

__device__ __forceinline__ float rcpfast(float x) {
#if __has_builtin(__builtin_amdgcn_rcpf)
  return __builtin_amdgcn_rcpf(x);
#else
  return 1.f / x;
#endif
}

#define AS1(p) ((const __attribute__((address_space(1))) void*)(uintptr_t)(p))
#define AS3(p) ((__attribute__((address_space(3))) void*)(uintptr_t)(p))

// ---------------------------------------------------------------------------
// fp32 -> bf16 bulk convert (8 elems/thread)
// ---------------------------------------------------------------------------
__global__ __launch_bounds__(256) void cvt_f32_bf16(
    const float* __restrict__ in, u16* __restrict__ out, int n8) {
  int i = blockIdx.x * 256 + threadIdx.x;
  if (i >= n8) return;
  const float4* p = (const float4*)in + 2 * (size_t)i;
  float4 a = p[0], b = p[1];
  uint4 o;
  o.x = (u32)f2b(a.x) | ((u32)f2b(a.y) << 16);
  o.y = (u32)f2b(a.z) | ((u32)f2b(a.w) << 16);
  o.z = (u32)f2b(b.x) | ((u32)f2b(b.y) << 16);
  o.w = (u32)f2b(b.z) | ((u32)f2b(b.w) << 16);
  ((uint4*)out)[i] = o;
}

// ---------------------------------------------------------------------------
// wt[n][k] = bf16(w[k][n])  — 64x64 LDS tile transpose (+1 pad, conflict-free)
// ---------------------------------------------------------------------------
__global__ __launch_bounds__(256) void transpose_cvt(
    const float* __restrict__ w, u16* __restrict__ wt, int K, int N) {
  __shared__ float t[64][65];
  const int n0 = blockIdx.x * 64, k0 = blockIdx.y * 64;
  const int c = threadIdx.x & 63, r4 = threadIdx.x >> 6;
#pragma unroll
  for (int j = 0; j < 16; ++j) {
    const int r = j * 4 + r4;
    t[c][r] = w[(size_t)(k0 + r) * N + n0 + c];
  }
  __syncthreads();
#pragma unroll
  for (int j = 0; j < 16; ++j) {
    const int nr = j * 4 + r4;
    wt[(size_t)(n0 + nr) * K + k0 + c] = f2b(t[nr][c]);
  }
}

// ---------------------------------------------------------------------------
// bf16 MFMA GEMM, m97 structure (unchanged from round 1; verified).
// ---------------------------------------------------------------------------
template <bool OUT_BF16>
__global__ __launch_bounds__(256) void gemm_kmajor(
    const u16* __restrict__ A, const u16* __restrict__ Bt,
    const float* __restrict__ bias, void* __restrict__ outp,
    int M, int N, int K, int nbx) {
  __shared__ __align__(16) u16 As[128 * 32];
  __shared__ __align__(16) u16 Bs[128 * 32];

  const int nwg = gridDim.x;
  const int qq = nwg >> 3, rr = nwg & 7;
  const int xcd = blockIdx.x & 7, off = blockIdx.x >> 3;
  const int wgid = (xcd < rr ? xcd * (qq + 1) : rr * (qq + 1) + (xcd - rr) * qq) + off;
  const int bx = wgid % nbx, by = wgid / nbx;
  const int row0 = by * 128, col0 = bx * 128;

  const int tid = threadIdx.x;
  const int w = tid >> 6, lane = tid & 63;
  const int wrow = (w >> 1) * 64, wcol = (w & 1) * 64;

  f32x4 acc[4][4];
#pragma unroll
  for (int a = 0; a < 4; ++a)
#pragma unroll
    for (int b = 0; b < 4; ++b)
#pragma unroll
      for (int e = 0; e < 4; ++e) acc[a][b][e] = 0.f;

  const size_t Kb = (size_t)K * 2;

  for (int k0 = 0; k0 < K; k0 += 32) {
#pragma unroll
    for (int c = 0; c < 4; ++c) {
      const int ch = w * 4 + c;
      const int i = ch & 7;
      const int rloc = i * 16 + (lane >> 2);
      const int kb = ((lane & 3) * 16) ^ ((rloc & 3) << 4);
      const char* src;
      char* dst;
      if (ch < 8) {
        src = (const char*)A + (size_t)(row0 + rloc) * Kb + k0 * 2 + kb;
        dst = (char*)As + i * 1024;
      } else {
        src = (const char*)Bt + (size_t)(col0 + rloc) * Kb + k0 * 2 + kb;
        dst = (char*)Bs + i * 1024;
      }
      __builtin_amdgcn_global_load_lds(AS1(src), AS3(dst), 16, 0, 0);
    }
    __syncthreads();

    bf16x8 af[4], bf[4];
#pragma unroll
    for (int rb = 0; rb < 4; ++rb) {
      const int rl = wrow + rb * 16 + (lane & 15);
      const int kb2 = ((lane >> 4) * 16) ^ ((rl & 3) << 4);
      af[rb] = *(const bf16x8*)((const char*)As + rl * 64 + kb2);
    }
#pragma unroll
    for (int cb = 0; cb < 4; ++cb) {
      const int rl = wcol + cb * 16 + (lane & 15);
      const int kb2 = ((lane >> 4) * 16) ^ ((rl & 3) << 4);
      bf[cb] = *(const bf16x8*)((const char*)Bs + rl * 64 + kb2);
    }
#pragma unroll
    for (int rb = 0; rb < 4; ++rb)
#pragma unroll
      for (int cb = 0; cb < 4; ++cb)
        acc[rb][cb] = __builtin_amdgcn_mfma_f32_16x16x32_bf16(
            af[rb], bf[cb], acc[rb][cb], 0, 0, 0);
    __syncthreads();
  }

#pragma unroll
  for (int cb = 0; cb < 4; ++cb) {
    const int colg = col0 + wcol + cb * 16 + (lane & 15);
    const float bv = bias[colg];
#pragma unroll
    for (int rb = 0; rb < 4; ++rb) {
#pragma unroll
      for (int i = 0; i < 4; ++i) {
        const int rowg = row0 + wrow + rb * 16 + (lane >> 4) * 4 + i;
        const float v = acc[rb][cb][i] + bv;
        if (OUT_BF16) {
          const u32 hv = f2b(v);
          const u32 pv = (u32)__shfl_xor((int)hv, 1);
          if (!(lane & 1))
            *(u32*)((u16*)outp + (size_t)rowg * N + colg) = hv | (pv << 16);
        } else {
          ((float*)outp)[(size_t)rowg * N + colg] = v;
        }
      }
    }
  }
}

// ---------------------------------------------------------------------------
// Flash attention v2: swapped QK^T (S^T), P fully in registers, per-lane
// softmax state, double-buffered K/V with 1 barrier/tile, paired q-tiles
// (31-pr, pr) for perfect load balance (512 blocks = 2/CU, 33 tiles each).
// ---------------------------------------------------------------------------
__global__ __launch_bounds__(256, 2) void attn_mfma2(
    const u16* __restrict__ qkvb, u16* __restrict__ yb) {
  // LDS: Ks dbuf 2x8KB at 0; Vt dbuf 2x8KB at 16KB
  __shared__ __align__(16) char lds[32768];

  const int bx = blockIdx.x;
  const int pr = bx >> 5;        // 0..15
  const int bh = bx & 31;
  const int bb = bh >> 4, h = bh & 15;

  const int tid = threadIdx.x;
  const int w = tid >> 6, lane = tid & 63;
  const int hh = lane >> 4, qh = lane & 15;

  const size_t rowb = 6144;  // 3072 bf16
  const char* base = (const char*)qkvb + (size_t)bb * SEQ * rowb;
  const int koffb = EMBD * 2 + h * 128;
  const int voffb = 2 * EMBD * 2 + h * 128;

  // K staging constants (8 chunks of 1024B; wave w does chunks 2w, 2w+1)
  const int krow_in_chunk = lane >> 3;  // 0..7
  // V staging constants: thread handles kv pair (vkv, vkv+1), d-group vdg
  const int vkv = (tid & 31) * 2;
  const int vdg = tid >> 5;  // 0..7, d = vdg*8+e

  for (int half = 0; half < 2; ++half) {
    const int qt = half ? pr : 31 - pr;
    const int q_abs = qt * 64 + w * 16 + qh;
    const int qloc = w * 16 + qh;

    // Q B-fragments: col=qh, k=d
    const char* qp = base + (size_t)q_abs * rowb + h * 128 + hh * 16;
    const bf16x8 qf0 = *(const bf16x8*)qp;
    const bf16x8 qf1 = *(const bf16x8*)(qp + 64);

    float m2 = -1e30f, l = 0.f;
    f32x4 of[4];
#pragma unroll
    for (int db = 0; db < 4; ++db)
#pragma unroll
      for (int e = 0; e < 4; ++e) of[db][e] = 0.f;

    // ---- prologue: stage tile kt=0 into buf 0 ----
    {
#pragma unroll
      for (int cc = 0; cc < 2; ++cc) {
        const int i = w * 2 + cc;
        const int kvl = i * 8 + krow_in_chunk;
        const int gs = (lane & 7) ^ ((i & 3) | ((krow_in_chunk & 1) << 2));
        const char* src = base + (size_t)kvl * rowb + koffb + gs * 16;
        __builtin_amdgcn_global_load_lds(AS1(src), AS3(lds + i * 1024), 16, 0, 0);
      }
      const char* vp = base + (size_t)vkv * rowb + voffb + vdg * 16;
      uint4 va = *(const uint4*)vp;
      uint4 vb = *(const uint4*)(vp + rowb);
      union { uint4 q; u16 s[8]; } ua, ub;
      ua.q = va; ub.q = vb;
      u32* vt = (u32*)(lds + 16384);
#pragma unroll
      for (int e = 0; e < 8; ++e) {
        const int d = vdg * 8 + e;
        vt[d * 32 + ((vkv >> 1) ^ ((d & 7) << 2))] =
            (u32)ua.s[e] | ((u32)ub.s[e] << 16);
      }
    }
    __syncthreads();

    for (int kt = 0; kt <= qt; ++kt) {
      const int cur = kt & 1;
      const char* ksb = lds + cur * 8192;
      const char* vtb = lds + 16384 + cur * 8192;

      // ---- prefetch tile kt+1 into buf cur^1 (issue early) ----
      uint4 va, vb;
      const bool pref = (kt < qt);
      if (pref) {
#pragma unroll
        for (int cc = 0; cc < 2; ++cc) {
          const int i = w * 2 + cc;
          const int kvl = i * 8 + krow_in_chunk;
          const int gs = (lane & 7) ^ ((i & 3) | ((krow_in_chunk & 1) << 2));
          const char* src =
              base + (size_t)((kt + 1) * 64 + kvl) * rowb + koffb + gs * 16;
          __builtin_amdgcn_global_load_lds(
              AS1(src), AS3(lds + (cur ^ 1) * 8192 + i * 1024), 16, 0, 0);
        }
        const char* vp =
            base + (size_t)((kt + 1) * 64 + vkv) * rowb + voffb + vdg * 16;
        va = *(const uint4*)vp;
        vb = *(const uint4*)(vp + rowb);
      }

      // ---- S^T = K Q^T via mfma(A=K permuted rows, B=Q) ----
      f32x4 st[4];
#pragma unroll
      for (int rb = 0; rb < 4; ++rb) {
#pragma unroll
        for (int e = 0; e < 4; ++e) st[rb][e] = 0.f;
        const int kv = 32 * (rb >> 1) + 8 * ((lane >> 2) & 3) + 4 * (rb & 1) +
                       (lane & 3);
        const int f = ((kv >> 3) & 3) | ((kv & 1) << 2);
        const char* rp = ksb + kv * 128;
        const bf16x8 k0 = *(const bf16x8*)(rp + ((hh * 16) ^ (f << 4)));
        const bf16x8 k1 = *(const bf16x8*)(rp + ((64 + hh * 16) ^ (f << 4)));
        st[rb] = __builtin_amdgcn_mfma_f32_16x16x32_bf16(k0, qf0, st[rb], 0, 0, 0);
        st[rb] = __builtin_amdgcn_mfma_f32_16x16x32_bf16(k1, qf1, st[rb], 0, 0, 0);
      }

      // ---- softmax (exp2 domain), per-lane state ----
      // lane's value (rb,i) is kv = 32*(rb>>1) + 8*hh + 4*(rb&1) + i
      const float C = 0.18033688f;  // 0.125 * log2(e)
      float pmax = -3.0e38f;
      if (kt == qt) {
#pragma unroll
        for (int rb = 0; rb < 4; ++rb) {
          const int kvb = 32 * (rb >> 1) + 8 * hh + 4 * (rb & 1);
#pragma unroll
          for (int i = 0; i < 4; ++i) {
            float v = st[rb][i] * C;
            if (kvb + i > qloc) v = -3.0e38f;
            st[rb][i] = v;
            pmax = fmaxf(pmax, v);
          }
        }
      } else {
#pragma unroll
        for (int rb = 0; rb < 4; ++rb)
#pragma unroll
          for (int i = 0; i < 4; ++i) {
            const float v = st[rb][i] * C;
            st[rb][i] = v;
            pmax = fmaxf(pmax, v);
          }
      }
      pmax = fmaxf(pmax, __shfl_xor(pmax, 16));
      pmax = fmaxf(pmax, __shfl_xor(pmax, 32));

      if (__any(pmax > m2 + 5.f)) {  // defer-max: rescale rarely
        const float mn = fmaxf(m2, pmax);
        const float al = exp2fast(m2 - mn);
        m2 = mn;
        l *= al;
#pragma unroll
        for (int db = 0; db < 4; ++db)
#pragma unroll
          for (int e = 0; e < 4; ++e) of[db][e] *= al;
      }

      float ls = 0.f;
#pragma unroll
      for (int rb = 0; rb < 4; ++rb)
#pragma unroll
        for (int i = 0; i < 4; ++i) {
          const float p = exp2fast(st[rb][i] - m2);
          st[rb][i] = p;
          ls += p;
        }
      ls += __shfl_xor(ls, 16);
      ls += __shfl_xor(ls, 32);
      l += ls;

      // ---- P -> bf16 B-fragments, fully in registers ----
      union { u32 wd[4]; bf16x8 v; } pf0, pf1;
      pf0.wd[0] = pkbf(st[0][0], st[0][1]);
      pf0.wd[1] = pkbf(st[0][2], st[0][3]);
      pf0.wd[2] = pkbf(st[1][0], st[1][1]);
      pf0.wd[3] = pkbf(st[1][2], st[1][3]);
      pf1.wd[0] = pkbf(st[2][0], st[2][1]);
      pf1.wd[1] = pkbf(st[2][2], st[2][3]);
      pf1.wd[2] = pkbf(st[3][0], st[3][1]);
      pf1.wd[3] = pkbf(st[3][2], st[3][3]);

      // ---- O^T += V^T P^T via mfma(A=Vt, B=P) ----
#pragma unroll
      for (int db = 0; db < 4; ++db) {
        const int d = db * 16 + qh;
        const int g = d & 7;
        const char* rp = vtb + d * 128;
        const bf16x8 v0 = *(const bf16x8*)(rp + ((hh * 16) ^ (g << 4)));
        const bf16x8 v1 = *(const bf16x8*)(rp + ((64 + hh * 16) ^ (g << 4)));
        of[db] = __builtin_amdgcn_mfma_f32_16x16x32_bf16(v0, pf0.v, of[db], 0, 0, 0);
        of[db] = __builtin_amdgcn_mfma_f32_16x16x32_bf16(v1, pf1.v, of[db], 0, 0, 0);
      }

      // ---- write prefetched V into buf cur^1 ----
      if (pref) {
        union { uint4 q; u16 s[8]; } ua, ub;
        ua.q = va; ub.q = vb;
        u32* vt = (u32*)(lds + 16384 + (cur ^ 1) * 8192);
#pragma unroll
        for (int e = 0; e < 8; ++e) {
          const int d = vdg * 8 + e;
          vt[d * 32 + ((vkv >> 1) ^ ((d & 7) << 2))] =
              (u32)ua.s[e] | ((u32)ub.s[e] << 16);
        }
      }
      __syncthreads();
    }

    // ---- epilogue: y[q][h*64+d] = O/l  (lane: q=qh, d=db*16+4*hh+i) ----
    const float inv = rcpfast(l);
    u16* yrow = yb + (size_t)(bb * SEQ + q_abs) * EMBD + h * 64;
#pragma unroll
    for (int db = 0; db < 4; ++db) {
      const u32 w0 = pkbf(of[db][0] * inv, of[db][1] * inv);
      const u32 w1 = pkbf(of[db][2] * inv, of[db][3] * inv);
      *(u32*)(yrow + db * 16 + 4 * hh) = w0;
      *(u32*)(yrow + db * 16 + 4 * hh + 2) = w1;
    }
    __syncthreads();  // safe restage for second q-tile
  }
}

// ---------------------------------------------------------------------------
extern "C" void kernel_launch(void* const* d_in, const int* in_sizes, int n_in,
                              void* d_out, int out_size, void* d_ws,
                              size_t ws_size, hipStream_t stream) {
  const float* x      = (const float*)d_in[0];
  const float* w_attn = (const float*)d_in[1];
  const float* b_attn = (const float*)d_in[2];
  const float* w_proj = (const float*)d_in[3];
  const float* b_proj = (const float*)d_in[4];
  float* out = (float*)d_out;

  u16* xb   = (u16*)d_ws;                          //  8 MB  [4096][1024]
  u16* wat  = xb + (size_t)M_ROWS * EMBD;          //  6 MB  [3072][1024]
  u16* wpt  = wat + (size_t)3 * EMBD * EMBD;       //  2 MB  [1024][1024]
  u16* qkvb = wpt + (size_t)EMBD * EMBD;           // 24 MB  [4096][3072]
  u16* yb   = qkvb + (size_t)M_ROWS * 3 * EMBD;    //  8 MB  [4096][1024]

  cvt_f32_bf16<<<(M_ROWS * EMBD / 8 + 255) / 256, 256, 0, stream>>>(
      x, xb, M_ROWS * EMBD / 8);
  transpose_cvt<<<dim3(3 * EMBD / 64, EMBD / 64), 256, 0, stream>>>(
      w_attn, wat, EMBD, 3 * EMBD);
  transpose_cvt<<<dim3(EMBD / 64, EMBD / 64), 256, 0, stream>>>(
      w_proj, wpt, EMBD, EMBD);

  gemm_kmajor<true><<<768, 256, 0, stream>>>(
      xb, wat, b_attn, qkvb, M_ROWS, 3 * EMBD, EMBD, 24);

  attn_mfma2<<<512, 256, 0, stream>>>(qkvb, yb);

  gemm_kmajor<false><<<256, 256, 0, stream>>>(
      yb, wpt, b_proj, out, M_ROWS, EMBD, EMBD, 8);
}

// Round 4
// 188.206 us; speedup vs baseline: 16.8534x; 1.1033x over previous
//
#include <hip/hip_runtime.h>
#include <stdint.h>

// B=2, T=2048, C=1024, H=16, D=64
#define SEQ   2048
#define EMBD  1024
#define M_ROWS 4096

typedef unsigned short u16;
typedef unsigned int u32;
typedef __attribute__((ext_vector_type(8))) short bf16x8;
typedef __attribute__((ext_vector_type(4))) float f32x4;

__device__ __forceinline__ u16 f2b(float f) {  // f32 -> bf16 RNE
  u32 x = __float_as_uint(f);
  return (u16)((x + 0x7FFFu + ((x >> 16) & 1u)) >> 16);
}

__device__ __forceinline__ u32 pkbf(float a, float b) {  // pack 2xf32 -> 2xbf16
  u32 r;
  asm("v_cvt_pk_bf16_f32 %0, %1, %2" : "=v"(r) : "v"(a), "v"(b));
  return r;
}

__device__ __forceinline__ float exp2fast(float x) {
#if __has_builtin(__builtin_amdgcn_exp2f)
  return __builtin_amdgcn_exp2f(x);
#else
  return __expf(x * 0.69314718f);
#endif
}

__device__ __forceinline__ float rcpfast(float x) {
#if __has_builtin(__builtin_amdgcn_rcpf)
  return __builtin_amdgcn_rcpf(x);
#else
  return 1.f / x;
#endif
}

#define AS1(p) ((const __attribute__((address_space(1))) void*)(uintptr_t)(p))
#define AS3(p) ((__attribute__((address_space(3))) void*)(uintptr_t)(p))

// ---------------------------------------------------------------------------
// fp32 -> bf16 bulk convert (8 elems/thread)
// ---------------------------------------------------------------------------
__global__ __launch_bounds__(256) void cvt_f32_bf16(
    const float* __restrict__ in, u16* __restrict__ out, int n8) {
  int i = blockIdx.x * 256 + threadIdx.x;
  if (i >= n8) return;
  const float4* p = (const float4*)in + 2 * (size_t)i;
  float4 a = p[0], b = p[1];
  uint4 o;
  o.x = (u32)f2b(a.x) | ((u32)f2b(a.y) << 16);
  o.y = (u32)f2b(a.z) | ((u32)f2b(a.w) << 16);
  o.z = (u32)f2b(b.x) | ((u32)f2b(b.y) << 16);
  o.w = (u32)f2b(b.z) | ((u32)f2b(b.w) << 16);
  ((uint4*)out)[i] = o;
}

// ---------------------------------------------------------------------------
// Fused weight transposes: wt[n][k] = bf16(w[k][n]) for w_attn and w_proj.
// grid (64, 16): bx<48 -> w_attn (N=3072), else w_proj (N=1024).
// ---------------------------------------------------------------------------
__global__ __launch_bounds__(256) void transpose_cvt2(
    const float* __restrict__ wa, u16* __restrict__ wat,
    const float* __restrict__ wp, u16* __restrict__ wpt) {
  __shared__ float t[64][65];
  const int bxr = blockIdx.x;
  const float* w = (bxr < 48) ? wa : wp;
  u16* wt = (bxr < 48) ? wat : wpt;
  const int N = (bxr < 48) ? 3072 : 1024;
  const int bx = (bxr < 48) ? bxr : bxr - 48;
  const int K = 1024;
  const int n0 = bx * 64, k0 = blockIdx.y * 64;
  const int c = threadIdx.x & 63, r4 = threadIdx.x >> 6;
#pragma unroll
  for (int j = 0; j < 16; ++j) {
    const int r = j * 4 + r4;
    t[c][r] = w[(size_t)(k0 + r) * N + n0 + c];
  }
  __syncthreads();
#pragma unroll
  for (int j = 0; j < 16; ++j) {
    const int nr = j * 4 + r4;
    wt[(size_t)(n0 + nr) * K + k0 + c] = f2b(t[nr][c]);
  }
}

// ---------------------------------------------------------------------------
// bf16 MFMA GEMM, 128x128 tile, BK=32, 4 waves, 2-phase double-buffered:
// one barrier per K-step; next tile's global_load_lds in flight across the
// current tile's ds_read+MFMA (T3 minimum recipe, m248: ~666 TF @K=1024).
// ---------------------------------------------------------------------------
template <bool OUT_BF16>
__global__ __launch_bounds__(256) void gemm_kmajor(
    const u16* __restrict__ A, const u16* __restrict__ Bt,
    const float* __restrict__ bias, void* __restrict__ outp,
    int M, int N, int K, int nbx) {
  __shared__ __align__(16) u16 sm[2][2][128 * 32];  // [buf][A/B][row*32+k]

  const int nwg = gridDim.x;
  const int qq = nwg >> 3, rr = nwg & 7;
  const int xcd = blockIdx.x & 7, off = blockIdx.x >> 3;
  const int wgid = (xcd < rr ? xcd * (qq + 1) : rr * (qq + 1) + (xcd - rr) * qq) + off;
  const int bx = wgid % nbx, by = wgid / nbx;
  const int row0 = by * 128, col0 = bx * 128;

  const int tid = threadIdx.x;
  const int w = tid >> 6, lane = tid & 63;
  const int wrow = (w >> 1) * 64, wcol = (w & 1) * 64;

  f32x4 acc[4][4];
#pragma unroll
  for (int a = 0; a < 4; ++a)
#pragma unroll
    for (int b = 0; b < 4; ++b)
#pragma unroll
      for (int e = 0; e < 4; ++e) acc[a][b][e] = 0.f;

  const size_t Kb = (size_t)K * 2;

  // staging: waves 0,1 -> A chunks 0..7; waves 2,3 -> B chunks 0..7
  auto stage = [&](int k0, int buf) {
#pragma unroll
    for (int c = 0; c < 4; ++c) {
      const int ch = w * 4 + c;
      const int i = ch & 7;
      const int rloc = i * 16 + (lane >> 2);
      const int kb = ((lane & 3) * 16) ^ ((rloc & 3) << 4);  // pre-swizzled src
      const u16* mat = (ch < 8) ? A : Bt;
      const int r0 = (ch < 8) ? row0 : col0;
      const char* src = (const char*)mat + (size_t)(r0 + rloc) * Kb + k0 * 2 + kb;
      char* dst = (char*)&sm[buf][(ch < 8) ? 0 : 1][0] + i * 1024;
      __builtin_amdgcn_global_load_lds(AS1(src), AS3(dst), 16, 0, 0);
    }
  };

  auto compute = [&](int buf) {
    bf16x8 af[4], bfr[4];
    const char* As = (const char*)&sm[buf][0][0];
    const char* Bs = (const char*)&sm[buf][1][0];
#pragma unroll
    for (int rb = 0; rb < 4; ++rb) {
      const int rl = wrow + rb * 16 + (lane & 15);
      const int kb2 = ((lane >> 4) * 16) ^ ((rl & 3) << 4);
      af[rb] = *(const bf16x8*)(As + rl * 64 + kb2);
    }
#pragma unroll
    for (int cb = 0; cb < 4; ++cb) {
      const int rl = wcol + cb * 16 + (lane & 15);
      const int kb2 = ((lane >> 4) * 16) ^ ((rl & 3) << 4);
      bfr[cb] = *(const bf16x8*)(Bs + rl * 64 + kb2);
    }
#pragma unroll
    for (int rb = 0; rb < 4; ++rb)
#pragma unroll
      for (int cb = 0; cb < 4; ++cb)
        acc[rb][cb] = __builtin_amdgcn_mfma_f32_16x16x32_bf16(
            af[rb], bfr[cb], acc[rb][cb], 0, 0, 0);
  };

  const int nt = K >> 5;  // 32-wide K tiles
  stage(0, 0);
  int cur = 0;
  for (int t = 0; t < nt - 1; ++t) {
    __syncthreads();              // buf[cur] ready (drains vmcnt+lgkm)
    stage((t + 1) * 32, cur ^ 1); // prefetch next tile (in flight over compute)
    compute(cur);
    cur ^= 1;
  }
  __syncthreads();
  compute(cur);

  // epilogue: C/D layout col=lane&15, row=(lane>>4)*4+i
#pragma unroll
  for (int cb = 0; cb < 4; ++cb) {
    const int colg = col0 + wcol + cb * 16 + (lane & 15);
    const float bv = bias[colg];
#pragma unroll
    for (int rb = 0; rb < 4; ++rb) {
#pragma unroll
      for (int i = 0; i < 4; ++i) {
        const int rowg = row0 + wrow + rb * 16 + (lane >> 4) * 4 + i;
        const float v = acc[rb][cb][i] + bv;
        if (OUT_BF16) {
          const u32 hv = f2b(v);
          const u32 pv = (u32)__shfl_xor((int)hv, 1);
          if (!(lane & 1))
            *(u32*)((u16*)outp + (size_t)rowg * N + colg) = hv | (pv << 16);
        } else {
          ((float*)outp)[(size_t)rowg * N + colg] = v;
        }
      }
    }
  }
}

// ---------------------------------------------------------------------------
// Flash attention: swapped QK^T (S^T), P fully in registers, per-lane
// softmax state, double-buffered K/V with 1 barrier/tile, paired q-tiles
// (31-pr, pr) for perfect load balance. + T5 setprio around MFMA clusters.
// ---------------------------------------------------------------------------
__global__ __launch_bounds__(256, 2) void attn_mfma2(
    const u16* __restrict__ qkvb, u16* __restrict__ yb) {
  __shared__ __align__(16) char lds[32768];

  const int bx = blockIdx.x;
  const int pr = bx >> 5;        // 0..15
  const int bh = bx & 31;
  const int bb = bh >> 4, h = bh & 15;

  const int tid = threadIdx.x;
  const int w = tid >> 6, lane = tid & 63;
  const int hh = lane >> 4, qh = lane & 15;

  const size_t rowb = 6144;  // 3072 bf16
  const char* base = (const char*)qkvb + (size_t)bb * SEQ * rowb;
  const int koffb = EMBD * 2 + h * 128;
  const int voffb = 2 * EMBD * 2 + h * 128;

  const int krow_in_chunk = lane >> 3;  // 0..7
  const int vkv = (tid & 31) * 2;
  const int vdg = tid >> 5;  // 0..7, d = vdg*8+e

  for (int half = 0; half < 2; ++half) {
    const int qt = half ? pr : 31 - pr;
    const int q_abs = qt * 64 + w * 16 + qh;
    const int qloc = w * 16 + qh;

    const char* qp = base + (size_t)q_abs * rowb + h * 128 + hh * 16;
    const bf16x8 qf0 = *(const bf16x8*)qp;
    const bf16x8 qf1 = *(const bf16x8*)(qp + 64);

    float m2 = -1e30f, l = 0.f;
    f32x4 of[4];
#pragma unroll
    for (int db = 0; db < 4; ++db)
#pragma unroll
      for (int e = 0; e < 4; ++e) of[db][e] = 0.f;

    // ---- prologue: stage tile kt=0 into buf 0 ----
    {
#pragma unroll
      for (int cc = 0; cc < 2; ++cc) {
        const int i = w * 2 + cc;
        const int kvl = i * 8 + krow_in_chunk;
        const int gs = (lane & 7) ^ ((i & 3) | ((krow_in_chunk & 1) << 2));
        const char* src = base + (size_t)kvl * rowb + koffb + gs * 16;
        __builtin_amdgcn_global_load_lds(AS1(src), AS3(lds + i * 1024), 16, 0, 0);
      }
      const char* vp = base + (size_t)vkv * rowb + voffb + vdg * 16;
      uint4 va = *(const uint4*)vp;
      uint4 vb = *(const uint4*)(vp + rowb);
      union { uint4 q; u16 s[8]; } ua, ub;
      ua.q = va; ub.q = vb;
      u32* vt = (u32*)(lds + 16384);
#pragma unroll
      for (int e = 0; e < 8; ++e) {
        const int d = vdg * 8 + e;
        vt[d * 32 + ((vkv >> 1) ^ ((d & 7) << 2))] =
            (u32)ua.s[e] | ((u32)ub.s[e] << 16);
      }
    }
    __syncthreads();

    for (int kt = 0; kt <= qt; ++kt) {
      const int cur = kt & 1;
      const char* ksb = lds + cur * 8192;
      const char* vtb = lds + 16384 + cur * 8192;

      // ---- prefetch tile kt+1 (issue early) ----
      uint4 va, vb;
      const bool pref = (kt < qt);
      if (pref) {
#pragma unroll
        for (int cc = 0; cc < 2; ++cc) {
          const int i = w * 2 + cc;
          const int kvl = i * 8 + krow_in_chunk;
          const int gs = (lane & 7) ^ ((i & 3) | ((krow_in_chunk & 1) << 2));
          const char* src =
              base + (size_t)((kt + 1) * 64 + kvl) * rowb + koffb + gs * 16;
          __builtin_amdgcn_global_load_lds(
              AS1(src), AS3(lds + (cur ^ 1) * 8192 + i * 1024), 16, 0, 0);
        }
        const char* vp =
            base + (size_t)((kt + 1) * 64 + vkv) * rowb + voffb + vdg * 16;
        va = *(const uint4*)vp;
        vb = *(const uint4*)(vp + rowb);
      }

      // ---- S^T = K Q^T ----
      f32x4 st[4];
      __builtin_amdgcn_s_setprio(1);
#pragma unroll
      for (int rb = 0; rb < 4; ++rb) {
#pragma unroll
        for (int e = 0; e < 4; ++e) st[rb][e] = 0.f;
        const int kv = 32 * (rb >> 1) + 8 * ((lane >> 2) & 3) + 4 * (rb & 1) +
                       (lane & 3);
        const int f = ((kv >> 3) & 3) | ((kv & 1) << 2);
        const char* rp = ksb + kv * 128;
        const bf16x8 k0 = *(const bf16x8*)(rp + ((hh * 16) ^ (f << 4)));
        const bf16x8 k1 = *(const bf16x8*)(rp + ((64 + hh * 16) ^ (f << 4)));
        st[rb] = __builtin_amdgcn_mfma_f32_16x16x32_bf16(k0, qf0, st[rb], 0, 0, 0);
        st[rb] = __builtin_amdgcn_mfma_f32_16x16x32_bf16(k1, qf1, st[rb], 0, 0, 0);
      }
      __builtin_amdgcn_s_setprio(0);

      // ---- softmax (exp2 domain), per-lane state ----
      const float C = 0.18033688f;  // 0.125 * log2(e)
      float pmax = -3.0e38f;
      if (kt == qt) {
#pragma unroll
        for (int rb = 0; rb < 4; ++rb) {
          const int kvb = 32 * (rb >> 1) + 8 * hh + 4 * (rb & 1);
#pragma unroll
          for (int i = 0; i < 4; ++i) {
            float v = st[rb][i] * C;
            if (kvb + i > qloc) v = -3.0e38f;
            st[rb][i] = v;
            pmax = fmaxf(pmax, v);
          }
        }
      } else {
#pragma unroll
        for (int rb = 0; rb < 4; ++rb)
#pragma unroll
          for (int i = 0; i < 4; ++i) {
            const float v = st[rb][i] * C;
            st[rb][i] = v;
            pmax = fmaxf(pmax, v);
          }
      }
      pmax = fmaxf(pmax, __shfl_xor(pmax, 16));
      pmax = fmaxf(pmax, __shfl_xor(pmax, 32));

      if (__any(pmax > m2 + 5.f)) {  // defer-max
        const float mn = fmaxf(m2, pmax);
        const float al = exp2fast(m2 - mn);
        m2 = mn;
        l *= al;
#pragma unroll
        for (int db = 0; db < 4; ++db)
#pragma unroll
          for (int e = 0; e < 4; ++e) of[db][e] *= al;
      }

      float ls = 0.f;
#pragma unroll
      for (int rb = 0; rb < 4; ++rb)
#pragma unroll
        for (int i = 0; i < 4; ++i) {
          const float p = exp2fast(st[rb][i] - m2);
          st[rb][i] = p;
          ls += p;
        }
      ls += __shfl_xor(ls, 16);
      ls += __shfl_xor(ls, 32);
      l += ls;

      union { u32 wd[4]; bf16x8 v; } pf0, pf1;
      pf0.wd[0] = pkbf(st[0][0], st[0][1]);
      pf0.wd[1] = pkbf(st[0][2], st[0][3]);
      pf0.wd[2] = pkbf(st[1][0], st[1][1]);
      pf0.wd[3] = pkbf(st[1][2], st[1][3]);
      pf1.wd[0] = pkbf(st[2][0], st[2][1]);
      pf1.wd[1] = pkbf(st[2][2], st[2][3]);
      pf1.wd[2] = pkbf(st[3][0], st[3][1]);
      pf1.wd[3] = pkbf(st[3][2], st[3][3]);

      // ---- O^T += V^T P^T ----
      __builtin_amdgcn_s_setprio(1);
#pragma unroll
      for (int db = 0; db < 4; ++db) {
        const int d = db * 16 + qh;
        const int g = d & 7;
        const char* rp = vtb + d * 128;
        const bf16x8 v0 = *(const bf16x8*)(rp + ((hh * 16) ^ (g << 4)));
        const bf16x8 v1 = *(const bf16x8*)(rp + ((64 + hh * 16) ^ (g << 4)));
        of[db] = __builtin_amdgcn_mfma_f32_16x16x32_bf16(v0, pf0.v, of[db], 0, 0, 0);
        of[db] = __builtin_amdgcn_mfma_f32_16x16x32_bf16(v1, pf1.v, of[db], 0, 0, 0);
      }
      __builtin_amdgcn_s_setprio(0);

      // ---- write prefetched V into buf cur^1 ----
      if (pref) {
        union { uint4 q; u16 s[8]; } ua, ub;
        ua.q = va; ub.q = vb;
        u32* vt = (u32*)(lds + 16384 + (cur ^ 1) * 8192);
#pragma unroll
        for (int e = 0; e < 8; ++e) {
          const int d = vdg * 8 + e;
          vt[d * 32 + ((vkv >> 1) ^ ((d & 7) << 2))] =
              (u32)ua.s[e] | ((u32)ub.s[e] << 16);
        }
      }
      __syncthreads();
    }

    // ---- epilogue ----
    const float inv = rcpfast(l);
    u16* yrow = yb + (size_t)(bb * SEQ + q_abs) * EMBD + h * 64;
#pragma unroll
    for (int db = 0; db < 4; ++db) {
      const u32 w0 = pkbf(of[db][0] * inv, of[db][1] * inv);
      const u32 w1 = pkbf(of[db][2] * inv, of[db][3] * inv);
      *(u32*)(yrow + db * 16 + 4 * hh) = w0;
      *(u32*)(yrow + db * 16 + 4 * hh + 2) = w1;
    }
    __syncthreads();  // safe restage for second q-tile
  }
}

// ---------------------------------------------------------------------------
extern "C" void kernel_launch(void* const* d_in, const int* in_sizes, int n_in,
                              void* d_out, int out_size, void* d_ws,
                              size_t ws_size, hipStream_t stream) {
  const float* x      = (const float*)d_in[0];
  const float* w_attn = (const float*)d_in[1];
  const float* b_attn = (const float*)d_in[2];
  const float* w_proj = (const float*)d_in[3];
  const float* b_proj = (const float*)d_in[4];
  float* out = (float*)d_out;

  u16* xb   = (u16*)d_ws;                          //  8 MB  [4096][1024]
  u16* wat  = xb + (size_t)M_ROWS * EMBD;          //  6 MB  [3072][1024]
  u16* wpt  = wat + (size_t)3 * EMBD * EMBD;       //  2 MB  [1024][1024]
  u16* qkvb = wpt + (size_t)EMBD * EMBD;           // 24 MB  [4096][3072]
  u16* yb   = qkvb + (size_t)M_ROWS * 3 * EMBD;    //  8 MB  [4096][1024]

  cvt_f32_bf16<<<(M_ROWS * EMBD / 8 + 255) / 256, 256, 0, stream>>>(
      x, xb, M_ROWS * EMBD / 8);
  transpose_cvt2<<<dim3(64, 16), 256, 0, stream>>>(w_attn, wat, w_proj, wpt);

  gemm_kmajor<true><<<768, 256, 0, stream>>>(
      xb, wat, b_attn, qkvb, M_ROWS, 3 * EMBD, EMBD, 24);

  attn_mfma2<<<512, 256, 0, stream>>>(qkvb, yb);

  gemm_kmajor<false><<<256, 256, 0, stream>>>(
      yb, wpt, b_proj, out, M_ROWS, EMBD, EMBD, 8);
}

// Round 5
// 184.515 us; speedup vs baseline: 17.1905x; 1.0200x over previous
//
#include <hip/hip_runtime.h>
#include <stdint.h>

// B=2, T=2048, C=1024, H=16, D=64
#define SEQ   2048
#define EMBD  1024
#define M_ROWS 4096

typedef unsigned short u16;
typedef unsigned int u32;
typedef __attribute__((ext_vector_type(8))) short bf16x8;
typedef __attribute__((ext_vector_type(4))) float f32x4;

__device__ __forceinline__ u16 f2b(float f) {  // f32 -> bf16 RNE
  u32 x = __float_as_uint(f);
  return (u16)((x + 0x7FFFu + ((x >> 16) & 1u)) >> 16);
}

__device__ __forceinline__ u32 pkbf(float a, float b) {  // pack 2xf32 -> 2xbf16
  u32 r;
  asm("v_cvt_pk_bf16_f32 %0, %1, %2" : "=v"(r) : "v"(a), "v"(b));
  return r;
}

__device__ __forceinline__ float exp2fast(float x) {
#if __has_builtin(__builtin_amdgcn_exp2f)
  return __builtin_amdgcn_exp2f(x);
#else
  return __expf(x * 0.69314718f);
#endif
}

__device__ __forceinline__ float rcpfast(float x) {
#if __has_builtin(__builtin_amdgcn_rcpf)
  return __builtin_amdgcn_rcpf(x);
#else
  return 1.f / x;
#endif
}

#define AS1(p) ((const __attribute__((address_space(1))) void*)(uintptr_t)(p))
#define AS3(p) ((__attribute__((address_space(3))) void*)(uintptr_t)(p))

// ---------------------------------------------------------------------------
// Fused prep: blocks 0..1023 convert x -> bf16 (16 elems/thread);
// blocks 1024..2047 transpose+convert the two weight matrices.
// ---------------------------------------------------------------------------
__global__ __launch_bounds__(256) void prep(
    const float* __restrict__ x, u16* __restrict__ xb,
    const float* __restrict__ wa, u16* __restrict__ wat,
    const float* __restrict__ wp, u16* __restrict__ wpt) {
  __shared__ float t[64][65];
  const int bx = blockIdx.x;
  if (bx < 1024) {
    const size_t idx = (size_t)bx * 256 + threadIdx.x;
    const float4* p = (const float4*)x + 4 * idx;
    uint4 o0, o1;
    {
      float4 a = p[0], b = p[1];
      o0.x = (u32)f2b(a.x) | ((u32)f2b(a.y) << 16);
      o0.y = (u32)f2b(a.z) | ((u32)f2b(a.w) << 16);
      o0.z = (u32)f2b(b.x) | ((u32)f2b(b.y) << 16);
      o0.w = (u32)f2b(b.z) | ((u32)f2b(b.w) << 16);
    }
    {
      float4 a = p[2], b = p[3];
      o1.x = (u32)f2b(a.x) | ((u32)f2b(a.y) << 16);
      o1.y = (u32)f2b(a.z) | ((u32)f2b(a.w) << 16);
      o1.z = (u32)f2b(b.x) | ((u32)f2b(b.y) << 16);
      o1.w = (u32)f2b(b.z) | ((u32)f2b(b.w) << 16);
    }
    ((uint4*)xb)[2 * idx] = o0;
    ((uint4*)xb)[2 * idx + 1] = o1;
    return;
  }
  const int tt = bx - 1024;
  const int bxr = tt & 63, by = tt >> 6;  // 64 n-tiles, 16 k-tiles
  const float* w = (bxr < 48) ? wa : wp;
  u16* wt = (bxr < 48) ? wat : wpt;
  const int N = (bxr < 48) ? 3072 : 1024;
  const int bxt = (bxr < 48) ? bxr : bxr - 48;
  const int K = 1024;
  const int n0 = bxt * 64, k0 = by * 64;
  const int c = threadIdx.x & 63, r4 = threadIdx.x >> 6;
#pragma unroll
  for (int j = 0; j < 16; ++j) {
    const int r = j * 4 + r4;
    t[c][r] = w[(size_t)(k0 + r) * N + n0 + c];
  }
  __syncthreads();
#pragma unroll
  for (int j = 0; j < 16; ++j) {
    const int nr = j * 4 + r4;
    wt[(size_t)(n0 + nr) * K + k0 + c] = f2b(t[nr][c]);
  }
}

// ---------------------------------------------------------------------------
// bf16 MFMA GEMM, 128x128 tile, BK=32, 4 waves, 2-phase double-buffered
// (unchanged from round 3; verified, ~645 TF @K=1024).
// ---------------------------------------------------------------------------
template <bool OUT_BF16>
__global__ __launch_bounds__(256) void gemm_kmajor(
    const u16* __restrict__ A, const u16* __restrict__ Bt,
    const float* __restrict__ bias, void* __restrict__ outp,
    int M, int N, int K, int nbx) {
  __shared__ __align__(16) u16 sm[2][2][128 * 32];  // [buf][A/B][row*32+k]

  const int nwg = gridDim.x;
  const int qq = nwg >> 3, rr = nwg & 7;
  const int xcd = blockIdx.x & 7, off = blockIdx.x >> 3;
  const int wgid = (xcd < rr ? xcd * (qq + 1) : rr * (qq + 1) + (xcd - rr) * qq) + off;
  const int bx = wgid % nbx, by = wgid / nbx;
  const int row0 = by * 128, col0 = bx * 128;

  const int tid = threadIdx.x;
  const int w = tid >> 6, lane = tid & 63;
  const int wrow = (w >> 1) * 64, wcol = (w & 1) * 64;

  f32x4 acc[4][4];
#pragma unroll
  for (int a = 0; a < 4; ++a)
#pragma unroll
    for (int b = 0; b < 4; ++b)
#pragma unroll
      for (int e = 0; e < 4; ++e) acc[a][b][e] = 0.f;

  const size_t Kb = (size_t)K * 2;

  auto stage = [&](int k0, int buf) {
#pragma unroll
    for (int c = 0; c < 4; ++c) {
      const int ch = w * 4 + c;
      const int i = ch & 7;
      const int rloc = i * 16 + (lane >> 2);
      const int kb = ((lane & 3) * 16) ^ ((rloc & 3) << 4);  // pre-swizzled src
      const u16* mat = (ch < 8) ? A : Bt;
      const int r0 = (ch < 8) ? row0 : col0;
      const char* src = (const char*)mat + (size_t)(r0 + rloc) * Kb + k0 * 2 + kb;
      char* dst = (char*)&sm[buf][(ch < 8) ? 0 : 1][0] + i * 1024;
      __builtin_amdgcn_global_load_lds(AS1(src), AS3(dst), 16, 0, 0);
    }
  };

  auto compute = [&](int buf) {
    bf16x8 af[4], bfr[4];
    const char* As = (const char*)&sm[buf][0][0];
    const char* Bs = (const char*)&sm[buf][1][0];
#pragma unroll
    for (int rb = 0; rb < 4; ++rb) {
      const int rl = wrow + rb * 16 + (lane & 15);
      const int kb2 = ((lane >> 4) * 16) ^ ((rl & 3) << 4);
      af[rb] = *(const bf16x8*)(As + rl * 64 + kb2);
    }
#pragma unroll
    for (int cb = 0; cb < 4; ++cb) {
      const int rl = wcol + cb * 16 + (lane & 15);
      const int kb2 = ((lane >> 4) * 16) ^ ((rl & 3) << 4);
      bfr[cb] = *(const bf16x8*)(Bs + rl * 64 + kb2);
    }
#pragma unroll
    for (int rb = 0; rb < 4; ++rb)
#pragma unroll
      for (int cb = 0; cb < 4; ++cb)
        acc[rb][cb] = __builtin_amdgcn_mfma_f32_16x16x32_bf16(
            af[rb], bfr[cb], acc[rb][cb], 0, 0, 0);
  };

  const int nt = K >> 5;
  stage(0, 0);
  int cur = 0;
  for (int t = 0; t < nt - 1; ++t) {
    __syncthreads();
    stage((t + 1) * 32, cur ^ 1);
    compute(cur);
    cur ^= 1;
  }
  __syncthreads();
  compute(cur);

#pragma unroll
  for (int cb = 0; cb < 4; ++cb) {
    const int colg = col0 + wcol + cb * 16 + (lane & 15);
    const float bv = bias[colg];
#pragma unroll
    for (int rb = 0; rb < 4; ++rb) {
#pragma unroll
      for (int i = 0; i < 4; ++i) {
        const int rowg = row0 + wrow + rb * 16 + (lane >> 4) * 4 + i;
        const float v = acc[rb][cb][i] + bv;
        if (OUT_BF16) {
          const u32 hv = f2b(v);
          const u32 pv = (u32)__shfl_xor((int)hv, 1);
          if (!(lane & 1))
            *(u32*)((u16*)outp + (size_t)rowg * N + colg) = hv | (pv << 16);
        } else {
          ((float*)outp)[(size_t)rowg * N + colg] = v;
        }
      }
    }
  }
}

// ---------------------------------------------------------------------------
// Flash attention: one 64-row q-tile per block, 1024 blocks (all resident,
// 4 blocks/CU = 16 waves/CU). Grid map: per-XCD bh locality (4 heads -> 2MB
// K/V in L2) + boustrophedon qt so each CU's 4 blocks sum to equal work.
// Swapped QK^T, P in registers, per-lane softmax, dbuf K/V, 1 barrier/tile.
// ---------------------------------------------------------------------------
__global__ __launch_bounds__(256, 4) void attn_mfma2(
    const u16* __restrict__ qkvb, u16* __restrict__ yb) {
  __shared__ __align__(16) char lds[32768];

  const int bx = blockIdx.x;
  const int xcd = bx & 7, g = bx >> 3;
  const int j = g >> 5, r = g & 31;
  const int bh = xcd * 4 + j;               // head-batch index, 4 per XCD
  const int qt = (j & 1) ? r : 31 - r;      // boustrophedon: CU work ~const
  const int bb = bh >> 4, h = bh & 15;

  const int tid = threadIdx.x;
  const int w = tid >> 6, lane = tid & 63;
  const int hh = lane >> 4, qh = lane & 15;

  const size_t rowb = 6144;  // 3072 bf16
  const char* base = (const char*)qkvb + (size_t)bb * SEQ * rowb;
  const int koffb = EMBD * 2 + h * 128;
  const int voffb = 2 * EMBD * 2 + h * 128;

  const int krow_in_chunk = lane >> 3;  // 0..7
  const int vkv = (tid & 31) * 2;
  const int vdg = tid >> 5;  // 0..7, d = vdg*8+e

  const int q_abs = qt * 64 + w * 16 + qh;
  const int qloc = w * 16 + qh;

  const char* qp = base + (size_t)q_abs * rowb + h * 128 + hh * 16;
  const bf16x8 qf0 = *(const bf16x8*)qp;
  const bf16x8 qf1 = *(const bf16x8*)(qp + 64);

  float m2 = -1e30f, l = 0.f;
  f32x4 of[4];
#pragma unroll
  for (int db = 0; db < 4; ++db)
#pragma unroll
    for (int e = 0; e < 4; ++e) of[db][e] = 0.f;

  // ---- prologue: stage tile kt=0 into buf 0 ----
  {
#pragma unroll
    for (int cc = 0; cc < 2; ++cc) {
      const int i = w * 2 + cc;
      const int kvl = i * 8 + krow_in_chunk;
      const int gs = (lane & 7) ^ ((i & 3) | ((krow_in_chunk & 1) << 2));
      const char* src = base + (size_t)kvl * rowb + koffb + gs * 16;
      __builtin_amdgcn_global_load_lds(AS1(src), AS3(lds + i * 1024), 16, 0, 0);
    }
    const char* vp = base + (size_t)vkv * rowb + voffb + vdg * 16;
    uint4 va = *(const uint4*)vp;
    uint4 vb = *(const uint4*)(vp + rowb);
    union { uint4 q; u16 s[8]; } ua, ub;
    ua.q = va; ub.q = vb;
    u32* vt = (u32*)(lds + 16384);
#pragma unroll
    for (int e = 0; e < 8; ++e) {
      const int d = vdg * 8 + e;
      vt[d * 32 + ((vkv >> 1) ^ ((d & 7) << 2))] =
          (u32)ua.s[e] | ((u32)ub.s[e] << 16);
    }
  }
  __syncthreads();

  for (int kt = 0; kt <= qt; ++kt) {
    const int cur = kt & 1;
    const char* ksb = lds + cur * 8192;
    const char* vtb = lds + 16384 + cur * 8192;

    // ---- prefetch tile kt+1 (issue early) ----
    uint4 va, vb;
    const bool pref = (kt < qt);
    if (pref) {
#pragma unroll
      for (int cc = 0; cc < 2; ++cc) {
        const int i = w * 2 + cc;
        const int kvl = i * 8 + krow_in_chunk;
        const int gs = (lane & 7) ^ ((i & 3) | ((krow_in_chunk & 1) << 2));
        const char* src =
            base + (size_t)((kt + 1) * 64 + kvl) * rowb + koffb + gs * 16;
        __builtin_amdgcn_global_load_lds(
            AS1(src), AS3(lds + (cur ^ 1) * 8192 + i * 1024), 16, 0, 0);
      }
      const char* vp =
          base + (size_t)((kt + 1) * 64 + vkv) * rowb + voffb + vdg * 16;
      va = *(const uint4*)vp;
      vb = *(const uint4*)(vp + rowb);
    }

    // ---- S^T = K Q^T (A rows permuted so output kv-slots match PV A-frag) ----
    f32x4 st[4];
    __builtin_amdgcn_s_setprio(1);
#pragma unroll
    for (int rb = 0; rb < 4; ++rb) {
#pragma unroll
      for (int e = 0; e < 4; ++e) st[rb][e] = 0.f;
      const int kv = 32 * (rb >> 1) + 8 * ((lane >> 2) & 3) + 4 * (rb & 1) +
                     (lane & 3);
      const int f = ((kv >> 3) & 3) | ((kv & 1) << 2);
      const char* rp = ksb + kv * 128;
      const bf16x8 k0 = *(const bf16x8*)(rp + ((hh * 16) ^ (f << 4)));
      const bf16x8 k1 = *(const bf16x8*)(rp + ((64 + hh * 16) ^ (f << 4)));
      st[rb] = __builtin_amdgcn_mfma_f32_16x16x32_bf16(k0, qf0, st[rb], 0, 0, 0);
      st[rb] = __builtin_amdgcn_mfma_f32_16x16x32_bf16(k1, qf1, st[rb], 0, 0, 0);
    }
    __builtin_amdgcn_s_setprio(0);

    // ---- softmax (exp2 domain), per-lane state ----
    // lane's value (rb,i) is kv = 32*(rb>>1) + 8*hh + 4*(rb&1) + i
    const float C = 0.18033688f;  // 0.125 * log2(e)
    float pmax = -3.0e38f;
    if (kt == qt) {
#pragma unroll
      for (int rb = 0; rb < 4; ++rb) {
        const int kvb = 32 * (rb >> 1) + 8 * hh + 4 * (rb & 1);
#pragma unroll
        for (int i = 0; i < 4; ++i) {
          float v = st[rb][i] * C;
          if (kvb + i > qloc) v = -3.0e38f;
          st[rb][i] = v;
          pmax = fmaxf(pmax, v);
        }
      }
    } else {
#pragma unroll
      for (int rb = 0; rb < 4; ++rb)
#pragma unroll
        for (int i = 0; i < 4; ++i) {
          const float v = st[rb][i] * C;
          st[rb][i] = v;
          pmax = fmaxf(pmax, v);
        }
    }
    pmax = fmaxf(pmax, __shfl_xor(pmax, 16));
    pmax = fmaxf(pmax, __shfl_xor(pmax, 32));

    if (__any(pmax > m2 + 5.f)) {  // defer-max
      const float mn = fmaxf(m2, pmax);
      const float al = exp2fast(m2 - mn);
      m2 = mn;
      l *= al;
#pragma unroll
      for (int db = 0; db < 4; ++db)
#pragma unroll
        for (int e = 0; e < 4; ++e) of[db][e] *= al;
    }

    float ls = 0.f;
#pragma unroll
    for (int rb = 0; rb < 4; ++rb)
#pragma unroll
      for (int i = 0; i < 4; ++i) {
        const float p = exp2fast(st[rb][i] - m2);
        st[rb][i] = p;
        ls += p;
      }
    ls += __shfl_xor(ls, 16);
    ls += __shfl_xor(ls, 32);
    l += ls;

    union { u32 wd[4]; bf16x8 v; } pf0, pf1;
    pf0.wd[0] = pkbf(st[0][0], st[0][1]);
    pf0.wd[1] = pkbf(st[0][2], st[0][3]);
    pf0.wd[2] = pkbf(st[1][0], st[1][1]);
    pf0.wd[3] = pkbf(st[1][2], st[1][3]);
    pf1.wd[0] = pkbf(st[2][0], st[2][1]);
    pf1.wd[1] = pkbf(st[2][2], st[2][3]);
    pf1.wd[2] = pkbf(st[3][0], st[3][1]);
    pf1.wd[3] = pkbf(st[3][2], st[3][3]);

    // ---- O^T += V^T P^T ----
    __builtin_amdgcn_s_setprio(1);
#pragma unroll
    for (int db = 0; db < 4; ++db) {
      const int d = db * 16 + qh;
      const int g2 = d & 7;
      const char* rp = vtb + d * 128;
      const bf16x8 v0 = *(const bf16x8*)(rp + ((hh * 16) ^ (g2 << 4)));
      const bf16x8 v1 = *(const bf16x8*)(rp + ((64 + hh * 16) ^ (g2 << 4)));
      of[db] = __builtin_amdgcn_mfma_f32_16x16x32_bf16(v0, pf0.v, of[db], 0, 0, 0);
      of[db] = __builtin_amdgcn_mfma_f32_16x16x32_bf16(v1, pf1.v, of[db], 0, 0, 0);
    }
    __builtin_amdgcn_s_setprio(0);

    // ---- write prefetched V into buf cur^1 ----
    if (pref) {
      union { uint4 q; u16 s[8]; } ua, ub;
      ua.q = va; ub.q = vb;
      u32* vt = (u32*)(lds + 16384 + (cur ^ 1) * 8192);
#pragma unroll
      for (int e = 0; e < 8; ++e) {
        const int d = vdg * 8 + e;
        vt[d * 32 + ((vkv >> 1) ^ ((d & 7) << 2))] =
            (u32)ua.s[e] | ((u32)ub.s[e] << 16);
      }
    }
    __syncthreads();
  }

  // ---- epilogue: y[q][h*64+d] = O/l  (lane: q=qh, d=db*16+4*hh+i) ----
  const float inv = rcpfast(l);
  u16* yrow = yb + (size_t)(bb * SEQ + q_abs) * EMBD + h * 64;
#pragma unroll
  for (int db = 0; db < 4; ++db) {
    const u32 w0 = pkbf(of[db][0] * inv, of[db][1] * inv);
    const u32 w1 = pkbf(of[db][2] * inv, of[db][3] * inv);
    *(u32*)(yrow + db * 16 + 4 * hh) = w0;
    *(u32*)(yrow + db * 16 + 4 * hh + 2) = w1;
  }
}

// ---------------------------------------------------------------------------
extern "C" void kernel_launch(void* const* d_in, const int* in_sizes, int n_in,
                              void* d_out, int out_size, void* d_ws,
                              size_t ws_size, hipStream_t stream) {
  const float* x      = (const float*)d_in[0];
  const float* w_attn = (const float*)d_in[1];
  const float* b_attn = (const float*)d_in[2];
  const float* w_proj = (const float*)d_in[3];
  const float* b_proj = (const float*)d_in[4];
  float* out = (float*)d_out;

  u16* xb   = (u16*)d_ws;                          //  8 MB  [4096][1024]
  u16* wat  = xb + (size_t)M_ROWS * EMBD;          //  6 MB  [3072][1024]
  u16* wpt  = wat + (size_t)3 * EMBD * EMBD;       //  2 MB  [1024][1024]
  u16* qkvb = wpt + (size_t)EMBD * EMBD;           // 24 MB  [4096][3072]
  u16* yb   = qkvb + (size_t)M_ROWS * 3 * EMBD;    //  8 MB  [4096][1024]

  prep<<<2048, 256, 0, stream>>>(x, xb, w_attn, wat, w_proj, wpt);

  gemm_kmajor<true><<<768, 256, 0, stream>>>(
      xb, wat, b_attn, qkvb, M_ROWS, 3 * EMBD, EMBD, 24);

  attn_mfma2<<<1024, 256, 0, stream>>>(qkvb, yb);

  gemm_kmajor<false><<<256, 256, 0, stream>>>(
      yb, wpt, b_proj, out, M_ROWS, EMBD, EMBD, 8);
}